// Round 1
// baseline (572.976 us; speedup 1.0000x reference)
//
#include <hip/hip_runtime.h>

// Segment mean: sums[s,c] = sum of x[p,c] where sp[p]==s ; out = sums / max(count,1)
// N = 2,097,152 pixels, C = 32 channels, S = 8192 segments (derived from out_size).

constexpr int C = 32;

__global__ void scatter_kernel(const float* __restrict__ x,
                               const int* __restrict__ sp,
                               float* __restrict__ sums,   // [S, C], pre-zeroed
                               float* __restrict__ counts, // [S], pre-zeroed
                               int n_pixels) {
    long long t = (long long)blockIdx.x * blockDim.x + threadIdx.x;
    long long p = t >> 5;          // pixel index
    int c = (int)(t & 31);         // channel index
    if (p >= n_pixels) return;
    int label = sp[p];             // broadcast within each 32-lane group (L1 hit)
    float v = x[p * C + c];        // wave reads 256 contiguous bytes — coalesced
    atomicAdd(&sums[(long long)label * C + c], v);
    if (c == 0) atomicAdd(&counts[label], 1.0f);
}

__global__ void divide_kernel(float* __restrict__ out,
                              const float* __restrict__ counts,
                              int total) {
    int t = blockIdx.x * blockDim.x + threadIdx.x;
    if (t >= total) return;
    int s = t >> 5;                // segment index (C == 32)
    float cnt = counts[s];
    out[t] = out[t] / fmaxf(cnt, 1.0f);
}

extern "C" void kernel_launch(void* const* d_in, const int* in_sizes, int n_in,
                              void* d_out, int out_size, void* d_ws, size_t ws_size,
                              hipStream_t stream) {
    const float* x  = (const float*)d_in[0];
    const int*   sp = (const int*)d_in[1];
    // d_in[2] = num_segments scalar; S also derivable as out_size / C.
    const int n_pixels = in_sizes[1];
    const int S = out_size / C;

    float* sums   = (float*)d_out;  // accumulate directly into output
    float* counts = (float*)d_ws;   // S floats of scratch

    // Harness re-poisons d_out / d_ws to 0xAA before every call — zero them.
    hipMemsetAsync(d_out, 0, sizeof(float) * (size_t)out_size, stream);
    hipMemsetAsync(counts, 0, sizeof(float) * (size_t)S, stream);

    const int block = 256;
    long long total_threads = (long long)n_pixels * C;
    long long grid = (total_threads + block - 1) / block;
    scatter_kernel<<<dim3((unsigned)grid), dim3(block), 0, stream>>>(
        x, sp, sums, counts, n_pixels);

    int total = out_size;
    divide_kernel<<<dim3((total + block - 1) / block), dim3(block), 0, stream>>>(
        sums, counts, total);
}

// Round 2
// 533.615 us; speedup vs baseline: 1.0738x; 1.0738x over previous
//
#include <hip/hip_runtime.h>

// Segment mean via counting-sort-by-label + atomic-free gather reduction.
// N = 2,097,152 pixels, C = 32 channels, S = 8192 segments.
// Round-1 post-mortem: 64M f32 device-scope atomics ran at ~206 G/s = 310 us
// (WRITE_SIZE 327 MB for a 1 MB logical output). Fix: sort pixel indices by
// label (2x 2M cheap int atomics), then gather-reduce with zero atomics.

constexpr int C = 32;

// ---------- phase 1: label histogram ----------
__global__ void hist_kernel(const int* __restrict__ sp, int* __restrict__ counts, int n) {
    int t = blockIdx.x * blockDim.x + threadIdx.x;
    if (t < n) atomicAdd(&counts[sp[t]], 1);
}

// ---------- phase 2: exclusive scan over S counts (single block) ----------
constexpr int SCAN_T = 1024;
__global__ __launch_bounds__(SCAN_T) void scan_kernel(const int* __restrict__ counts,
                                                      int* __restrict__ seg_start,
                                                      int* __restrict__ cursor, int S) {
    __shared__ int partial[SCAN_T];
    const int t = threadIdx.x;
    const int per = (S + SCAN_T - 1) / SCAN_T;   // 8 for S=8192
    const int base = t * per;
    int local[8];
    int sum = 0;
    #pragma unroll
    for (int i = 0; i < 8; i++) {
        int idx = base + i;
        int v = (i < per && idx < S) ? counts[idx] : 0;
        local[i] = v;
        sum += v;
    }
    partial[t] = sum;
    __syncthreads();
    // Hillis-Steele inclusive scan over per-thread partials
    for (int off = 1; off < SCAN_T; off <<= 1) {
        int v = (t >= off) ? partial[t - off] : 0;
        __syncthreads();
        partial[t] += v;
        __syncthreads();
    }
    int excl = (t == 0) ? 0 : partial[t - 1];
    #pragma unroll
    for (int i = 0; i < 8; i++) {
        int idx = base + i;
        if (i < per && idx < S) {
            seg_start[idx] = excl;
            cursor[idx]    = excl;
            excl += local[i];
        }
    }
}

// ---------- phase 3: scatter pixel indices into label-sorted order ----------
__global__ void scatter_idx_kernel(const int* __restrict__ sp, int* __restrict__ cursor,
                                   int* __restrict__ order, int n) {
    int t = blockIdx.x * blockDim.x + threadIdx.x;
    if (t < n) {
        int s = sp[t];
        int pos = atomicAdd(&cursor[s], 1);
        order[pos] = t;
    }
}

// ---------- phase 4: per-segment gather + mean (one wave per segment) ----------
__global__ __launch_bounds__(64) void segment_mean_kernel(const float4* __restrict__ x4,
                                                          const int* __restrict__ order,
                                                          const int* __restrict__ seg_start,
                                                          const int* __restrict__ counts,
                                                          float4* __restrict__ out4) {
    const int s = blockIdx.x;
    const int start = seg_start[s];
    const int cnt = counts[s];
    const int t = threadIdx.x;          // 0..63
    const int slot = t >> 3;            // 0..7 : pixel slot within wave
    const int cg = t & 7;               // 0..7 : float4 channel-group
    float4 acc = {0.f, 0.f, 0.f, 0.f};
    // Wave processes 8 pixels per iteration; each lane does one 16 B load
    // (64 lanes x 16 B = 1 KB per instruction, rows are 128 B-aligned).
    for (int i = slot; i < cnt; i += 8) {
        int p = order[start + i];       // 8 distinct addrs/wave, coalesced
        float4 v = x4[p * 8 + cg];
        acc.x += v.x; acc.y += v.y; acc.z += v.z; acc.w += v.w;
    }
    // Reduce across the 8 slots (lane stride 8): +32, +16, +8
    #pragma unroll
    for (int d = 32; d >= 8; d >>= 1) {
        acc.x += __shfl_down(acc.x, d);
        acc.y += __shfl_down(acc.y, d);
        acc.z += __shfl_down(acc.z, d);
        acc.w += __shfl_down(acc.w, d);
    }
    if (t < 8) {
        float inv = (cnt > 0) ? 1.0f / (float)cnt : 0.0f;
        float4 r;
        r.x = acc.x * inv; r.y = acc.y * inv; r.z = acc.z * inv; r.w = acc.w * inv;
        out4[s * 8 + t] = r;            // 8 lanes x 16 B = 128 B coalesced store
    }
}

// ---------- fallback (round-1 atomic path) if workspace is too small ----------
__global__ void fb_scatter_kernel(const float* __restrict__ x, const int* __restrict__ sp,
                                  float* __restrict__ sums, float* __restrict__ fcounts,
                                  int n_pixels) {
    long long t = (long long)blockIdx.x * blockDim.x + threadIdx.x;
    long long p = t >> 5;
    int c = (int)(t & 31);
    if (p >= n_pixels) return;
    int label = sp[p];
    float v = x[p * C + c];
    atomicAdd(&sums[(long long)label * C + c], v);
    if (c == 0) atomicAdd(&fcounts[label], 1.0f);
}
__global__ void fb_divide_kernel(float* __restrict__ out, const float* __restrict__ fcounts,
                                 int total) {
    int t = blockIdx.x * blockDim.x + threadIdx.x;
    if (t >= total) return;
    out[t] = out[t] / fmaxf(fcounts[t >> 5], 1.0f);
}

extern "C" void kernel_launch(void* const* d_in, const int* in_sizes, int n_in,
                              void* d_out, int out_size, void* d_ws, size_t ws_size,
                              hipStream_t stream) {
    const float* x  = (const float*)d_in[0];
    const int*   sp = (const int*)d_in[1];
    const int n = in_sizes[1];
    const int S = out_size / C;

    const size_t need = (size_t)(3 * S + n) * sizeof(int);
    if (ws_size >= need) {
        int* counts    = (int*)d_ws;      // [S]  (must be zeroed: ws is poisoned)
        int* seg_start = counts + S;      // [S]
        int* cursor    = seg_start + S;   // [S]
        int* order     = cursor + S;      // [N]

        hipMemsetAsync(counts, 0, (size_t)S * sizeof(int), stream);
        hist_kernel<<<(n + 255) / 256, 256, 0, stream>>>(sp, counts, n);
        scan_kernel<<<1, SCAN_T, 0, stream>>>(counts, seg_start, cursor, S);
        scatter_idx_kernel<<<(n + 255) / 256, 256, 0, stream>>>(sp, cursor, order, n);
        segment_mean_kernel<<<S, 64, 0, stream>>>((const float4*)x, order, seg_start,
                                                  counts, (float4*)d_out);
    } else {
        float* sums    = (float*)d_out;
        float* fcounts = (float*)d_ws;
        hipMemsetAsync(d_out, 0, sizeof(float) * (size_t)out_size, stream);
        hipMemsetAsync(fcounts, 0, sizeof(float) * (size_t)S, stream);
        long long total_threads = (long long)n * C;
        fb_scatter_kernel<<<dim3((unsigned)((total_threads + 255) / 256)), 256, 0, stream>>>(
            x, sp, sums, fcounts, n);
        fb_divide_kernel<<<(out_size + 255) / 256, 256, 0, stream>>>(sums, fcounts, out_size);
    }
}